// Round 8
// baseline (648.447 us; speedup 1.0000x reference)
//
#include <hip/hip_runtime.h>
#include <hip/hip_bf16.h>

typedef __hip_bfloat16 bf16;

#define NEG_SLOPE 0.01f
#define FGW 0.1f

__device__ __forceinline__ float b2f(bf16 v) { return __bfloat162float(v); }

// flagged boundary load: isbf=1 -> data is bf16, else f32
__device__ __forceinline__ float ldf(const void* p, size_t i, int isbf) {
    return isbf ? b2f(((const bf16*)p)[i]) : ((const float*)p)[i];
}

// bf16 bits (ushort) <-> float
__device__ __forceinline__ float bu2f(unsigned short u) {
    return __uint_as_float(((unsigned)u) << 16);
}
__device__ __forceinline__ unsigned short f2bu(float f) {
    return __bfloat16_as_ushort(__float2bfloat16(f));  // RNE
}

__device__ __forceinline__ float waveReduceSum(float v) {
#pragma unroll
    for (int o = 32; o > 0; o >>= 1) v += __shfl_down(v, o, 64);
    return v;
}

#define ATOMIC_ADD_F32(p, v) unsafeAtomicAdd((p), (v))

// ---------------- degree histogram + fused dtype detect + sscal zero ----------------
__global__ __launch_bounds__(256) void k_degdet(const int* __restrict__ ei, int* __restrict__ deg, int E,
                                                const unsigned short* __restrict__ xr,
                                                float* __restrict__ sscal, int* __restrict__ flag) {
    if (blockIdx.x == 0) {
        int t = threadIdx.x;
        if (t < 64) {
            int big = 0;
            for (int i = t; i < 256; i += 64) {
                int ex = (xr[i] >> 7) & 0xFF;
                if (ex >= 0xBF) big = 1;   // |bf16| >= 2^64 impossible for N(0,1) data
            }
            unsigned long long m = __ballot(big);
            if (t == 0) {
                *flag = (m == 0ull) ? 1 : 0;  // 1 => tensors are bf16
                sscal[0] = 0.f; sscal[1] = 0.f;
            }
        }
    }
    int e = blockIdx.x * 256 + threadIdx.x;
    if (e < E) atomicAdd(&deg[ei[E + e]], 1);
}

// ---------------- single-block 1024-thread scan: deg -> rowptr; also zeroes cursor ----------------
__global__ __launch_bounds__(1024) void k_scan(const int* __restrict__ deg, int* __restrict__ rowptr,
                                               int* __restrict__ cursor, int N) {
    __shared__ int part[1024];
    const int t = threadIdx.x;
    const int per = (N + 1023) / 1024;
    const int i0 = t * per;
    const int i1 = min(N, i0 + per);
    int s = 0;
    for (int i = i0; i < i1; i++) s += deg[i];
    part[t] = s;
    __syncthreads();
    for (int o = 1; o < 1024; o <<= 1) {
        int add = (t >= o) ? part[t - o] : 0;
        __syncthreads();
        part[t] += add;
        __syncthreads();
    }
    int excl = part[t] - s;
    for (int i = i0; i < i1; i++) {
        rowptr[i] = excl;
        excl += deg[i];
        cursor[i] = 0;
    }
    if (t == 1023) rowptr[N] = part[1023];
}

__global__ __launch_bounds__(256) void k_scatter(const int* __restrict__ ei, const int* __restrict__ rowptr,
                                                 int* __restrict__ cursor, int* __restrict__ csr_src, int E) {
    int e = blockIdx.x * 256 + threadIdx.x;
    if (e >= E) return;
    int d = ei[E + e];
    int pos = atomicAdd(&cursor[d], 1);
    csr_src[rowptr[d] + pos] = ei[e];
}

// ---------------- GEMM1 fused: h1(bf16) = x@W1 ; pk1 = {ar[4], logr, h1c} ; al1 ; rwsum ----------------
__global__ __launch_bounds__(256) void k_gemm1f(const void* __restrict__ x,
                                                const void* __restrict__ W,
                                                const void* __restrict__ attl,
                                                const void* __restrict__ attr,
                                                unsigned short* __restrict__ h1,
                                                float* __restrict__ pk1,     // [N][8]
                                                float* __restrict__ al1,
                                                float* __restrict__ rwS,
                                                int N, const int* __restrict__ flag) {
    const int isbf = *flag;
    __shared__ float xs[16][128];
    __shared__ float rpart[16];
    const int row0 = blockIdx.x * 16;
    const int t = threadIdx.x;
#pragma unroll
    for (int i = 0; i < 8; i++) {
        int idx = t + i * 256;
        int r = idx >> 7, c = idx & 127;
        xs[r][c] = ldf(x, (size_t)(row0 + r) * 128 + c, isbf);
    }
    __syncthreads();
    const int j = t;  // column 0..255; wave w = j>>6 == head
    float acc[16];
#pragma unroll
    for (int r = 0; r < 16; r++) acc[r] = 0.f;
    for (int k = 0; k < 128; k += 4) {
        float w0 = ldf(W, (size_t)(k + 0) * 256 + j, isbf);
        float w1 = ldf(W, (size_t)(k + 1) * 256 + j, isbf);
        float w2 = ldf(W, (size_t)(k + 2) * 256 + j, isbf);
        float w3 = ldf(W, (size_t)(k + 3) * 256 + j, isbf);
#pragma unroll
        for (int r = 0; r < 16; r++) {
            float4 xv = *reinterpret_cast<const float4*>(&xs[r][k]);
            acc[r] += xv.x * w0 + xv.y * w1 + xv.z * w2 + xv.w * w3;
        }
    }
#pragma unroll
    for (int r = 0; r < 16; r++) {
        h1[(size_t)(row0 + r) * 256 + j] = f2bu(acc[r]);
        if (j == 255) pk1[(size_t)(row0 + r) * 8 + 5] = acc[r];  // fp32 sidecar col 255
    }

    // fused stats: wave w reduces head w (cols w*64..w*64+63)
    const int w = t >> 6, lane = t & 63;
    float avl = ldf(attl, j, isbf);
    float avr = ldf(attr, j, isbf);
#pragma unroll
    for (int r = 0; r < 16; r++) {
        float sl = waveReduceSum(acc[r] * avl);
        float sr = waveReduceSum(acc[r] * avr);
        if (lane == 0) {
            al1[(row0 + r) * 4 + w] = sl;
            pk1[(size_t)(row0 + r) * 8 + w] = sr;
        }
    }
    // fused reward weight: x col 127 is in LDS
    if (t < 16) {
        float a = fabsf(xs[t][127]);
        float rr = 1.f / (a + 1e-6f);
        pk1[(size_t)(row0 + t) * 8 + 4] = logf(rr);
        rpart[t] = rr;
    }
    __syncthreads();
    if (t == 0) {
        float s = 0.f;
#pragma unroll
        for (int i = 0; i < 16; i++) s += rpart[i];
        ATOMIC_ADD_F32(rwS, s);
    }
}

// ---------------- layer1 aggregation: online softmax (single fast exp), packed gathers ----------------
__global__ __launch_bounds__(256) void k_agg1(const int* __restrict__ rowptr,
                                              const int* __restrict__ csr_src,
                                              const float* __restrict__ al1,
                                              const float* __restrict__ pk1,
                                              const float* __restrict__ rwS,
                                              const unsigned short* __restrict__ h1,
                                              float* __restrict__ x2, int N) {
    int d = blockIdx.x * 4 + (threadIdx.x >> 6);
    if (d >= N) return;
    int lane = threadIdx.x & 63;
    int h = lane >> 4;                 // head for this lane's 4 features
    const float gl = FGW * logf(fmaxf(*rwS, 1e-12f));
    float al_h = al1[d * 4 + h];
    int beg = rowptr[d], end = rowptr[d + 1];
    float m = -INFINITY, sum = 0.f;
    float4 acc = {0.f, 0.f, 0.f, 0.f};
    if (beg < end) {
        int s = csr_src[beg];
        float arv = pk1[(size_t)s * 8 + h];
        float lg  = pk1[(size_t)s * 8 + 4];
        float c255 = pk1[(size_t)s * 8 + 5];
        uint2 hb = *reinterpret_cast<const uint2*>(&h1[(size_t)s * 256 + lane * 4]);
        for (int i = beg; i < end; i++) {
            float c_ar = arv, c_lg = lg, c_c255 = c255;
            uint2 c_hb = hb;
            if (i + 1 < end) {  // wave-uniform prefetch of next edge
                int s2 = csr_src[i + 1];
                arv = pk1[(size_t)s2 * 8 + h];
                lg  = pk1[(size_t)s2 * 8 + 4];
                c255 = pk1[(size_t)s2 * 8 + 5];
                hb = *reinterpret_cast<const uint2*>(&h1[(size_t)s2 * 256 + lane * 4]);
            }
            float a = al_h + c_ar;
            a = fmaxf(a, NEG_SLOPE * a);          // leaky_relu
            a = fmaf(FGW, c_lg, a - gl);          // + FGW*(log r - log S)
            // single-exp online softmax: one of {e,f} is exp(0)=1
            float mn = fmaxf(m, a);
            float g = __expf(fminf(m, a) - mn);   // exp(-|m-a|); 0 on first edge
            bool up = a > m;
            float f = up ? g : 1.0f;
            float e = up ? 1.0f : g;
            sum = fmaf(sum, f, e);
            float v0 = __uint_as_float(c_hb.x << 16);
            float v1 = __uint_as_float(c_hb.x & 0xFFFF0000u);
            float v2 = __uint_as_float(c_hb.y << 16);
            float v3 = __uint_as_float(c_hb.y & 0xFFFF0000u);
            v3 = (lane == 63) ? c_c255 : v3;      // exact fp32 for log-sensitive col 255
            acc.x = fmaf(acc.x, f, e * v0);
            acc.y = fmaf(acc.y, f, e * v1);
            acc.z = fmaf(acc.z, f, e * v2);
            acc.w = fmaf(acc.w, f, e * v3);
            m = mn;
        }
    }
    float inv = 1.f / (sum + 1e-16f);
    float4 o;
    o.x = acc.x * inv; o.y = acc.y * inv; o.z = acc.z * inv; o.w = acc.w * inv;
    o.x = (o.x > 0.f) ? o.x : expm1f(o.x);
    o.y = (o.y > 0.f) ? o.y : expm1f(o.y);
    o.z = (o.z > 0.f) ? o.z : expm1f(o.z);
    o.w = (o.w > 0.f) ? o.w : expm1f(o.w);
    *reinterpret_cast<float4*>(&x2[(size_t)d * 256 + lane * 4]) = o;
}

// ---------------- GEMM2 fused: h2(bf16) = x2@W2 ; pk2 = {ar2, logr2} ; al2 ; rwsum2 ----------------
__global__ __launch_bounds__(256) void k_gemm2f(const float* __restrict__ x2,
                                                const void* __restrict__ W,
                                                const void* __restrict__ attl,
                                                const void* __restrict__ attr,
                                                unsigned short* __restrict__ h2,
                                                float* __restrict__ pk2,     // [N][2]
                                                float* __restrict__ al2,
                                                float* __restrict__ rwS2,
                                                int N, const int* __restrict__ flag) {
    const int isbf = *flag;
    __shared__ float xs[16][256];
    __shared__ float rpart[16];
    const int row0 = blockIdx.x * 16;
    const int t = threadIdx.x;
#pragma unroll
    for (int i = 0; i < 16; i++) {
        int idx = t + i * 256;
        int r = idx >> 8, c = idx & 255;
        xs[r][c] = x2[(size_t)(row0 + r) * 256 + c];
    }
    __syncthreads();
    const int j = t & 63, rg = t >> 6;   // wave rg handles rows rg*4..rg*4+3
    float acc[4] = {0.f, 0.f, 0.f, 0.f};
    for (int k = 0; k < 256; k += 4) {
        float w0 = ldf(W, (size_t)(k + 0) * 64 + j, isbf);
        float w1 = ldf(W, (size_t)(k + 1) * 64 + j, isbf);
        float w2 = ldf(W, (size_t)(k + 2) * 64 + j, isbf);
        float w3 = ldf(W, (size_t)(k + 3) * 64 + j, isbf);
#pragma unroll
        for (int i = 0; i < 4; i++) {
            float4 xv = *reinterpret_cast<const float4*>(&xs[rg * 4 + i][k]);
            acc[i] += xv.x * w0 + xv.y * w1 + xv.z * w2 + xv.w * w3;
        }
    }
    float avl = ldf(attl, j, isbf);
    float avr = ldf(attr, j, isbf);
#pragma unroll
    for (int i = 0; i < 4; i++) {
        int row = row0 + rg * 4 + i;
        h2[(size_t)row * 64 + j] = f2bu(acc[i]);
        float sl = waveReduceSum(acc[i] * avl);
        float sr = waveReduceSum(acc[i] * avr);
        if (j == 0) { al2[row] = sl; pk2[(size_t)row * 2] = sr; }
    }
    // fused reward weight: x2 col 255 (fp32) in LDS
    if (t < 16) {
        float a = fabsf(xs[t][255]);
        float rr = 1.f / (a + 1e-6f);
        pk2[(size_t)(row0 + t) * 2 + 1] = logf(rr);
        rpart[t] = rr;
    }
    __syncthreads();
    if (t == 0) {
        float s = 0.f;
#pragma unroll
        for (int i = 0; i < 16; i++) s += rpart[i];
        ATOMIC_ADD_F32(rwS2, s);
    }
}

// ---------------- layer2 aggregation + ELU + FC -> y (single fast exp) ----------------
__global__ __launch_bounds__(256) void k_agg2(const int* __restrict__ rowptr,
                                              const int* __restrict__ csr_src,
                                              const float* __restrict__ al2,
                                              const float* __restrict__ pk2,
                                              const float* __restrict__ rwS2,
                                              const unsigned short* __restrict__ h2,
                                              const void* __restrict__ fcw,
                                              const void* __restrict__ fcb,
                                              void* __restrict__ y, int N,
                                              const int* __restrict__ flag) {
    const int isbf = *flag;
    int d = blockIdx.x * 4 + (threadIdx.x >> 6);
    if (d >= N) return;
    int lane = threadIdx.x & 63;
    const float gl2 = FGW * logf(fmaxf(*rwS2, 1e-12f));
    float al_d = al2[d];
    int beg = rowptr[d], end = rowptr[d + 1];
    float m = -INFINITY, sum = 0.f, acc = 0.f;
    if (beg < end) {
        int s = csr_src[beg];
        float2 pv = *reinterpret_cast<const float2*>(&pk2[(size_t)s * 2]);
        float hvs = bu2f(h2[(size_t)s * 64 + lane]);
        for (int i = beg; i < end; i++) {
            float2 c_pv = pv;
            float c_h = hvs;
            if (i + 1 < end) {
                int s2 = csr_src[i + 1];
                pv = *reinterpret_cast<const float2*>(&pk2[(size_t)s2 * 2]);
                hvs = bu2f(h2[(size_t)s2 * 64 + lane]);
            }
            float a = al_d + c_pv.x;
            a = fmaxf(a, NEG_SLOPE * a);
            a = fmaf(FGW, c_pv.y, a - gl2);
            float mn = fmaxf(m, a);
            float g = __expf(fminf(m, a) - mn);
            bool up = a > m;
            float f = up ? g : 1.0f;
            float e = up ? 1.0f : g;
            sum = fmaf(sum, f, e);
            acc = fmaf(acc, f, e * c_h);
            m = mn;
        }
    }
    float v = acc / (sum + 1e-16f);
    v = (v > 0.f) ? v : expm1f(v);
    float r = waveReduceSum(v * ldf(fcw, lane, isbf));
    if (lane == 0) {
        float o = r + ldf(fcb, 0, isbf);
        if (isbf) ((bf16*)y)[d] = __float2bfloat16(o);
        else      ((float*)y)[d] = o;
    }
}

extern "C" void kernel_launch(void* const* d_in, const int* in_sizes, int n_in,
                              void* d_out, int out_size, void* d_ws, size_t ws_size,
                              hipStream_t stream) {
    const void* x     = d_in[0];
    const int*  ei    = (const int*)d_in[1];
    const void* W1    = d_in[2];
    const void* attl1 = d_in[3];
    const void* attr1 = d_in[4];
    const void* W2    = d_in[5];
    const void* attl2 = d_in[6];
    const void* attr2 = d_in[7];
    const void* fcw   = d_in[8];
    const void* fcb   = d_in[9];

    const int N = in_sizes[0] / 128;  // 50000
    const int E = in_sizes[1] / 2;    // 800000

    // ---- workspace layout (4-byte units unless noted), ~84 MB ----
    float* p = (float*)d_ws;
    unsigned short* h1 = (unsigned short*)p; p += (size_t)N * 128;  // N*256 bf16
    float* pk1    = p; p += (size_t)N * 8;   // {ar[4], logr, h1c, pad, pad} per node
    float* al1    = p; p += (size_t)N * 4;
    float* x2     = p; p += (size_t)N * 256;
    float* pk2    = p; p += (size_t)N * 2;   // {ar2, logr2} per node
    float* al2    = p; p += (size_t)N;
    int* rowptr   = (int*)p; p += (size_t)N + 1;
    int* deg      = (int*)p; p += (size_t)N;
    int* cursor   = (int*)p; p += (size_t)N;
    int* csr_src  = (int*)p; p += (size_t)E;
    float* sscal  = p; p += 4;               // [0]=rwsum L1, [1]=rwsum L2, [2]=dtype flag
    int* dflag = (int*)(sscal + 2);

    unsigned short* h2 = h1;   // layer2 bf16 h2 (N*64) overlays h1 region (dead after agg1)

    // deg must be zero before the histogram (ws re-poisoned each call)
    hipMemsetAsync(deg, 0, (size_t)N * 4, stream);

    // ---- CSR build over dst (+ fused dtype detect + sscal zero) ----
    k_degdet<<<(E + 255) / 256, 256, 0, stream>>>(ei, deg, E, (const unsigned short*)x, sscal, dflag);
    k_scan<<<1, 1024, 0, stream>>>(deg, rowptr, cursor, N);
    k_scatter<<<(E + 255) / 256, 256, 0, stream>>>(ei, rowptr, cursor, csr_src, E);

    // ---- layer 1 ----
    k_gemm1f<<<N / 16, 256, 0, stream>>>(x, W1, attl1, attr1, h1, pk1, al1,
                                         &sscal[0], N, dflag);
    k_agg1<<<(N + 3) / 4, 256, 0, stream>>>(rowptr, csr_src, al1, pk1,
                                            &sscal[0], h1, x2, N);

    // ---- layer 2 ----
    k_gemm2f<<<N / 16, 256, 0, stream>>>(x2, W2, attl2, attr2, h2, pk2, al2,
                                         &sscal[1], N, dflag);
    k_agg2<<<(N + 3) / 4, 256, 0, stream>>>(rowptr, csr_src, al2, pk2,
                                            &sscal[1], h2, fcw, fcb, d_out, N, dflag);
}